// Round 1
// baseline (495.632 us; speedup 1.0000x reference)
//
#include <hip/hip_runtime.h>

// Problem constants
#define NBOOKS 4
#define CODES  1024
#define DIM    64
#define NPOS   32768          // B*T*H*W
#define CCH    256            // NB*DIM (channel dim of z)
#define QSIZE  8388608        // 4*256*8*32*32
#define ENC_OFF  8388608
#define LOSS_OFF 8519680      // QSIZE + 131072
#define PERP_OFF 8519681

// workspace byte offsets
#define WS_E2    0            // 4096 floats
#define WS_IDX   16384        // 131072 ints
#define WS_CNT   540672       // 4096 ints
#define WS_PART  557056       // 512 floats

// ---------------------------------------------------------------- e2 = ||e||^2
__global__ void k_e2(const float* __restrict__ emb, float* __restrict__ e2) {
    int i = blockIdx.x * 256 + threadIdx.x;            // 0..4095 = k*1024+c
    const float4* e = (const float4*)(emb + ((size_t)i << 6));
    float s = 0.f;
#pragma unroll
    for (int j = 0; j < 16; ++j) {
        float4 v = e[j];
        s += v.x * v.x + v.y * v.y + v.z * v.z + v.w * v.w;
    }
    e2[i] = s;
}

// ---------------------------------------------------------------- argmin
// thread = one (book k, position n). x[64] in VGPRs; embedding reads are
// wave-uniform -> scalar loads; VALU does nearly pure v_fma_f32.
__global__ void __launch_bounds__(256) k_argmin(
        const float* __restrict__ z, const float* __restrict__ emb,
        const float* __restrict__ e2, int* __restrict__ idxbuf) {
    int tid = threadIdx.x;
    int n = blockIdx.x * 256 + tid;     // position 0..32767
    int k = blockIdx.y;                 // book
    int b = n >> 13;                    // batch
    int s = n & 8191;                   // spatial t*1024+h*32+w

    const float* zp = z + (((size_t)(b * CCH + k * DIM)) << 13) + s;
    float x[DIM];
#pragma unroll
    for (int d = 0; d < DIM; ++d) x[d] = zp[(size_t)d << 13];

    const float* ek  = emb + ((size_t)k << 16);   // k*1024*64
    const float* e2k = e2 + (k << 10);

    float best = 3.402823466e+38f;
    int   bi   = 0;
    for (int c = 0; c < CODES; ++c) {
        const float* e = ek + ((size_t)c << 6);
        float a0 = 0.f, a1 = 0.f, a2 = 0.f, a3 = 0.f;
#pragma unroll
        for (int d = 0; d < DIM; d += 4) {
            a0 = fmaf(x[d + 0], e[d + 0], a0);
            a1 = fmaf(x[d + 1], e[d + 1], a1);
            a2 = fmaf(x[d + 2], e[d + 2], a2);
            a3 = fmaf(x[d + 3], e[d + 3], a3);
        }
        float dot  = (a0 + a1) + (a2 + a3);
        float dist = fmaf(-2.f, dot, e2k[c]);      // x^2 omitted: constant per n
        if (dist < best) { best = dist; bi = c; }  // strict <: first-min tie-break
    }
    idxbuf[(k << 15) + n] = bi;
}

// ---------------------------------------------------------------- gather+loss
__global__ void __launch_bounds__(256) k_quant(
        const float* __restrict__ z, const float* __restrict__ emb,
        const int* __restrict__ idxbuf, float* __restrict__ out,
        int* __restrict__ counts, float* __restrict__ partial) {
    int tid = threadIdx.x;
    int n = blockIdx.x * 256 + tid;
    int k = blockIdx.y;
    int b = n >> 13;
    int s = n & 8191;

    int bi = idxbuf[(k << 15) + n];
    const float4* e = (const float4*)(emb + ((size_t)k << 16) + ((size_t)bi << 6));
    size_t base = (((size_t)(b * CCH + k * DIM)) << 13) + s;
    const float* zp = z + base;
    float* qp = out + base;

    float sq = 0.f;
#pragma unroll
    for (int j = 0; j < 16; ++j) {
        float4 q4 = e[j];
        int d = j * 4;
        float z0 = zp[(size_t)(d + 0) << 13];
        float z1 = zp[(size_t)(d + 1) << 13];
        float z2 = zp[(size_t)(d + 2) << 13];
        float z3 = zp[(size_t)(d + 3) << 13];
        qp[(size_t)(d + 0) << 13] = q4.x;
        qp[(size_t)(d + 1) << 13] = q4.y;
        qp[(size_t)(d + 2) << 13] = q4.z;
        qp[(size_t)(d + 3) << 13] = q4.w;
        float d0 = z0 - q4.x; sq = fmaf(d0, d0, sq);
        float d1 = z1 - q4.y; sq = fmaf(d1, d1, sq);
        float d2 = z2 - q4.z; sq = fmaf(d2, d2, sq);
        float d3 = z3 - q4.w; sq = fmaf(d3, d3, sq);
    }

    // encodings (B,T,H,W,NB) flat = n*4 + k, written as float (out buffer is f32)
    out[ENC_OFF + (size_t)n * NBOOKS + k] = (float)bi;

    atomicAdd(&counts[(k << 10) + bi], 1);

    // deterministic block partial sum of (z-q)^2
    for (int off = 32; off; off >>= 1) sq += __shfl_down(sq, off, 64);
    __shared__ float red[4];
    if ((tid & 63) == 0) red[tid >> 6] = sq;
    __syncthreads();
    if (tid == 0)
        partial[blockIdx.y * gridDim.x + blockIdx.x] = (red[0] + red[1]) + (red[2] + red[3]);
}

// ---------------------------------------------------------------- finalize
__global__ void __launch_bounds__(256) k_fin(
        const int* __restrict__ counts, const float* __restrict__ partial,
        float* __restrict__ out) {
    __shared__ float sh[256];
    int tid = threadIdx.x;

    // deterministic sum of 512 block partials
    float s = partial[tid] + partial[tid + 256];
    sh[tid] = s;
    __syncthreads();
    for (int off = 128; off; off >>= 1) {
        if (tid < off) sh[tid] += sh[tid + off];
        __syncthreads();
    }
    if (tid == 0) out[LOSS_OFF] = 0.25f * sh[0] / 8388608.f;

    // perplexity
    float psum = 0.f;
    for (int k = 0; k < NBOOKS; ++k) {
        float h = 0.f;
        for (int c = tid; c < CODES; c += 256) {
            float p = (float)counts[(k << 10) + c] * (1.f / 32768.f);
            h += p * logf(p + 1e-10f);
        }
        __syncthreads();
        sh[tid] = h;
        __syncthreads();
        for (int off = 128; off; off >>= 1) {
            if (tid < off) sh[tid] += sh[tid + off];
            __syncthreads();
        }
        if (tid == 0) psum += expf(-sh[0]);
        __syncthreads();
    }
    if (tid == 0) out[PERP_OFF] = psum * (1.f / NBOOKS);
}

// ----------------------------------------------------------------
extern "C" void kernel_launch(void* const* d_in, const int* in_sizes, int n_in,
                              void* d_out, int out_size, void* d_ws, size_t ws_size,
                              hipStream_t stream) {
    const float* z   = (const float*)d_in[0];
    const float* emb = (const float*)d_in[1];
    float* out = (float*)d_out;
    char* ws = (char*)d_ws;

    float* e2      = (float*)(ws + WS_E2);
    int*   idxbuf  = (int*)(ws + WS_IDX);
    int*   counts  = (int*)(ws + WS_CNT);
    float* partial = (float*)(ws + WS_PART);

    hipMemsetAsync(counts, 0, CODES * NBOOKS * sizeof(int), stream);

    k_e2<<<16, 256, 0, stream>>>(emb, e2);

    dim3 grid(NPOS / 256, NBOOKS);
    k_argmin<<<grid, 256, 0, stream>>>(z, emb, e2, idxbuf);
    k_quant<<<grid, 256, 0, stream>>>(z, emb, idxbuf, out, counts, partial);
    k_fin<<<1, 256, 0, stream>>>(counts, partial, out);
}

// Round 2
// 204.525 us; speedup vs baseline: 2.4233x; 2.4233x over previous
//
#include <hip/hip_runtime.h>

// Problem constants
#define NBOOKS 4
#define CODES  1024
#define DIM    64
#define NPOS   32768          // B*T*H*W
#define CCH    256            // NB*DIM (channel dim of z)
#define ENC_OFF  8388608
#define LOSS_OFF 8519680
#define PERP_OFF 8519681

// workspace byte offsets
#define WS_E2      0              // 4096 f32 = 16 KB
#define WS_EHI     16384          // 4096*64 bf16 = 512 KB
#define WS_ELO     540672         // 512 KB
#define WS_IDX     1064960        // 131072 int = 512 KB
#define WS_CNT     1589248        // 4096 int = 16 KB
#define WS_PART    1605632        // 512 f32 = 2 KB
#define WS_FLAGCNT 1607680        // 1 int (pad 16)
#define WS_FLAGS   1607696        // 131072 int = 512 KB

#define MARGIN 0.0625f

typedef __bf16 bf16x8 __attribute__((ext_vector_type(8)));
typedef __bf16 bf16x4 __attribute__((ext_vector_type(4)));
typedef float  f32x4  __attribute__((ext_vector_type(4)));

// ---------------------------------------------------------------- e2 = ||e||^2
__global__ void k_e2(const float* __restrict__ emb, float* __restrict__ e2) {
    int i = blockIdx.x * 256 + threadIdx.x;            // 0..4095 = k*1024+c
    const float4* e = (const float4*)(emb + ((size_t)i << 6));
    float s = 0.f;
#pragma unroll
    for (int j = 0; j < 16; ++j) {
        float4 v = e[j];
        s += v.x * v.x + v.y * v.y + v.z * v.z + v.w * v.w;
    }
    e2[i] = s;
}

// ---------------------------------------------------------------- E -> bf16 hi/lo
__global__ void k_eprep(const float* __restrict__ emb,
                        __bf16* __restrict__ ehi, __bf16* __restrict__ elo) {
    int i = blockIdx.x * 256 + threadIdx.x;            // 0..65535, 4 elems each
    float4 v = ((const float4*)emb)[i];
    bf16x4 hv, lv;
    float f;
    f = v.x; hv[0] = (__bf16)f; lv[0] = (__bf16)(f - (float)hv[0]);
    f = v.y; hv[1] = (__bf16)f; lv[1] = (__bf16)(f - (float)hv[1]);
    f = v.z; hv[2] = (__bf16)f; lv[2] = (__bf16)(f - (float)hv[2]);
    f = v.w; hv[3] = (__bf16)f; lv[3] = (__bf16)(f - (float)hv[3]);
    *(bf16x4*)&ehi[(size_t)i * 4] = hv;
    *(bf16x4*)&elo[(size_t)i * 4] = lv;
}

// ---------------------------------------------------------------- MFMA argmin
// Block: 64 positions x all 1024 codes for one book. 4 waves, each owns 16
// code-tiles (16 codes each). Orientation: A = codes (M), B = positions (N),
// so D[code][pos]; each lane owns positions col=lane&15 -> argmin is
// lane-local. 3-term bf16 split; near-ties (gap < MARGIN) flagged for exact
// fp32 rescore.
__global__ void __launch_bounds__(256) k_argmin_mfma(
        const float* __restrict__ z, const float* __restrict__ e2g,
        const __bf16* __restrict__ ehi, const __bf16* __restrict__ elo,
        int* __restrict__ idxbuf, int* __restrict__ flagcnt,
        int* __restrict__ flaglist) {
    __shared__ __attribute__((aligned(16))) __bf16 sXhi[4096];  // [d8][pos][8]
    __shared__ __attribute__((aligned(16))) __bf16 sXlo[4096];
    __shared__ float sm1[256], sm2[256];
    __shared__ int   si1[256];

    int tid = threadIdx.x;
    int wave = tid >> 6, lane = tid & 63;
    int lrow = lane >> 4, lcol = lane & 15;
    int k = blockIdx.y;
    int posbase = blockIdx.x * 64;
    int b = posbase >> 13, s0 = posbase & 8191;

    const float* zb = z + (((size_t)(b * CCH + k * DIM)) << 13) + s0;

    // ---- stage X tile: 64 pos x 64 dims -> bf16 hi/lo in LDS
    {
        int pos = tid & 63, dg = tid >> 6;
#pragma unroll
        for (int pass = 0; pass < 2; ++pass) {
            int d8 = dg + pass * 4;
            bf16x8 hv, lv;
#pragma unroll
            for (int j = 0; j < 8; ++j) {
                float f = zb[((size_t)(d8 * 8 + j) << 13) + pos];
                __bf16 h = (__bf16)f;
                hv[j] = h;
                lv[j] = (__bf16)(f - (float)h);
            }
            *(bf16x8*)&sXhi[(d8 * 64 + pos) * 8] = hv;
            *(bf16x8*)&sXlo[(d8 * 64 + pos) * 8] = lv;
        }
    }
    __syncthreads();

    const __bf16* ehik = ehi + ((size_t)k << 16);
    const __bf16* elok = elo + ((size_t)k << 16);
    const float*  e2k  = e2g + (k << 10);

    float m1[4], m2[4];
    int   i1[4];
#pragma unroll
    for (int pt = 0; pt < 4; ++pt) { m1[pt] = 3.4e38f; m2[pt] = 3.4e38f; i1[pt] = 0; }

    for (int it = 0; it < 16; ++it) {
        int ct = wave * 16 + it;            // code-tile index 0..63
        int acode = ct * 16 + lcol;         // A-row this lane loads
        const __bf16* eph = ehik + acode * 64 + lrow * 8;
        const __bf16* epl = elok + acode * 64 + lrow * 8;
        bf16x8 eh0 = *(const bf16x8*)(eph);
        bf16x8 eh1 = *(const bf16x8*)(eph + 32);
        bf16x8 el0 = *(const bf16x8*)(epl);
        bf16x8 el1 = *(const bf16x8*)(epl + 32);
        f32x4 e2v = *(const f32x4*)(e2k + ct * 16 + lrow * 4);

#pragma unroll
        for (int pt = 0; pt < 4; ++pt) {
            int xb = pt * 16 + lcol;        // position within block
            bf16x8 xh0 = *(const bf16x8*)&sXhi[(lrow * 64 + xb) * 8];
            bf16x8 xl0 = *(const bf16x8*)&sXlo[(lrow * 64 + xb) * 8];
            bf16x8 xh1 = *(const bf16x8*)&sXhi[((4 + lrow) * 64 + xb) * 8];
            bf16x8 xl1 = *(const bf16x8*)&sXlo[((4 + lrow) * 64 + xb) * 8];
            f32x4 acc = {0.f, 0.f, 0.f, 0.f};
            acc = __builtin_amdgcn_mfma_f32_16x16x32_bf16(eh0, xh0, acc, 0, 0, 0);
            acc = __builtin_amdgcn_mfma_f32_16x16x32_bf16(eh0, xl0, acc, 0, 0, 0);
            acc = __builtin_amdgcn_mfma_f32_16x16x32_bf16(el0, xh0, acc, 0, 0, 0);
            acc = __builtin_amdgcn_mfma_f32_16x16x32_bf16(eh1, xh1, acc, 0, 0, 0);
            acc = __builtin_amdgcn_mfma_f32_16x16x32_bf16(eh1, xl1, acc, 0, 0, 0);
            acc = __builtin_amdgcn_mfma_f32_16x16x32_bf16(el1, xh1, acc, 0, 0, 0);
#pragma unroll
            for (int r = 0; r < 4; ++r) {
                float dist = fmaf(-2.f, acc[r], e2v[r]);
                int c = ct * 16 + lrow * 4 + r;
                bool lt = dist < m1[pt];
                m2[pt] = lt ? m1[pt] : fminf(dist, m2[pt]);
                i1[pt] = lt ? c : i1[pt];
                m1[pt] = lt ? dist : m1[pt];
            }
        }
    }

    // ---- merge across lane-groups (4 lanes hold same position)
#pragma unroll
    for (int off = 16; off < 64; off <<= 1) {
#pragma unroll
        for (int pt = 0; pt < 4; ++pt) {
            float om1 = __shfl_xor(m1[pt], off);
            float om2 = __shfl_xor(m2[pt], off);
            int   oi  = __shfl_xor(i1[pt], off);
            bool take = (om1 < m1[pt]) || (om1 == m1[pt] && oi < i1[pt]);
            float loser = take ? m1[pt] : om1;
            m2[pt] = fminf(fminf(m2[pt], om2), loser);
            m1[pt] = take ? om1 : m1[pt];
            i1[pt] = take ? oi  : i1[pt];
        }
    }
    if (lane < 16) {
#pragma unroll
        for (int pt = 0; pt < 4; ++pt) {
            int p = pt * 16 + lane;
            sm1[wave * 64 + p] = m1[pt];
            sm2[wave * 64 + p] = m2[pt];
            si1[wave * 64 + p] = i1[pt];
        }
    }
    __syncthreads();

    // ---- merge across 4 waves, write idx, flag near-ties
    if (tid < 64) {
        float a1 = sm1[tid], a2 = sm2[tid];
        int   ai = si1[tid];
#pragma unroll
        for (int w = 1; w < 4; ++w) {
            float b1 = sm1[w * 64 + tid], b2 = sm2[w * 64 + tid];
            int   bi = si1[w * 64 + tid];
            bool take = (b1 < a1) || (b1 == a1 && bi < ai);
            float loser = take ? a1 : b1;
            a2 = fminf(fminf(a2, b2), loser);
            if (take) { a1 = b1; ai = bi; }
        }
        int n = posbase + tid;
        idxbuf[(k << 15) + n] = ai;
        if (a2 - a1 < MARGIN) {
            int slot = atomicAdd(flagcnt, 1);
            flaglist[slot] = (k << 15) + n;
        }
    }
}

// ---------------------------------------------------------------- exact rescore
__global__ void __launch_bounds__(256) k_rescore(
        const float* __restrict__ z, const float* __restrict__ emb,
        const float* __restrict__ e2g, const int* __restrict__ flagcnt,
        const int* __restrict__ flaglist, int* __restrict__ idxbuf) {
    __shared__ float xsh[64];
    __shared__ float rm[256];
    __shared__ int   ri[256];
    int tid = threadIdx.x;
    int nf = *flagcnt;
    for (int e = blockIdx.x; e < nf; e += gridDim.x) {
        int gp = flaglist[e];
        int k = gp >> 15, n = gp & 32767;
        int b = n >> 13, s = n & 8191;
        if (tid < 64)
            xsh[tid] = z[(((size_t)(b * CCH + k * DIM + tid)) << 13) + s];
        __syncthreads();
        float best = 3.4e38f;
        int   bi = 0;
        for (int c = tid; c < CODES; c += 256) {
            const float* ev = emb + ((size_t)k << 16) + ((size_t)c << 6);
            float a0 = 0.f, a1 = 0.f, a2 = 0.f, a3 = 0.f;
#pragma unroll
            for (int d = 0; d < DIM; d += 4) {
                a0 = fmaf(xsh[d + 0], ev[d + 0], a0);
                a1 = fmaf(xsh[d + 1], ev[d + 1], a1);
                a2 = fmaf(xsh[d + 2], ev[d + 2], a2);
                a3 = fmaf(xsh[d + 3], ev[d + 3], a3);
            }
            float dot = (a0 + a1) + (a2 + a3);
            float dist = fmaf(-2.f, dot, e2g[(k << 10) + c]);
            if (dist < best) { best = dist; bi = c; }
        }
        rm[tid] = best; ri[tid] = bi;
        __syncthreads();
        for (int off = 128; off; off >>= 1) {
            if (tid < off) {
                float bv = rm[tid + off]; int bx = ri[tid + off];
                if (bv < rm[tid] || (bv == rm[tid] && bx < ri[tid])) {
                    rm[tid] = bv; ri[tid] = bx;
                }
            }
            __syncthreads();
        }
        if (tid == 0) idxbuf[(k << 15) + n] = ri[0];
        __syncthreads();
    }
}

// ---------------------------------------------------------------- gather+loss
__global__ void __launch_bounds__(256) k_quant(
        const float* __restrict__ z, const float* __restrict__ emb,
        const int* __restrict__ idxbuf, float* __restrict__ out,
        int* __restrict__ counts, float* __restrict__ partial) {
    int tid = threadIdx.x;
    int n = blockIdx.x * 256 + tid;
    int k = blockIdx.y;
    int b = n >> 13;
    int s = n & 8191;

    int bi = idxbuf[(k << 15) + n];
    const float4* e = (const float4*)(emb + ((size_t)k << 16) + ((size_t)bi << 6));
    size_t base = (((size_t)(b * CCH + k * DIM)) << 13) + s;
    const float* zp = z + base;
    float* qp = out + base;

    float sq = 0.f;
#pragma unroll
    for (int j = 0; j < 16; ++j) {
        float4 q4 = e[j];
        int d = j * 4;
        float z0 = zp[(size_t)(d + 0) << 13];
        float z1 = zp[(size_t)(d + 1) << 13];
        float z2 = zp[(size_t)(d + 2) << 13];
        float z3 = zp[(size_t)(d + 3) << 13];
        qp[(size_t)(d + 0) << 13] = q4.x;
        qp[(size_t)(d + 1) << 13] = q4.y;
        qp[(size_t)(d + 2) << 13] = q4.z;
        qp[(size_t)(d + 3) << 13] = q4.w;
        float d0 = z0 - q4.x; sq = fmaf(d0, d0, sq);
        float d1 = z1 - q4.y; sq = fmaf(d1, d1, sq);
        float d2 = z2 - q4.z; sq = fmaf(d2, d2, sq);
        float d3 = z3 - q4.w; sq = fmaf(d3, d3, sq);
    }

    out[ENC_OFF + (size_t)n * NBOOKS + k] = (float)bi;
    atomicAdd(&counts[(k << 10) + bi], 1);

    for (int off = 32; off; off >>= 1) sq += __shfl_down(sq, off, 64);
    __shared__ float red[4];
    if ((tid & 63) == 0) red[tid >> 6] = sq;
    __syncthreads();
    if (tid == 0)
        partial[blockIdx.y * gridDim.x + blockIdx.x] = (red[0] + red[1]) + (red[2] + red[3]);
}

// ---------------------------------------------------------------- finalize
__global__ void __launch_bounds__(256) k_fin(
        const int* __restrict__ counts, const float* __restrict__ partial,
        float* __restrict__ out) {
    __shared__ float sh[256];
    int tid = threadIdx.x;

    float s = partial[tid] + partial[tid + 256];
    sh[tid] = s;
    __syncthreads();
    for (int off = 128; off; off >>= 1) {
        if (tid < off) sh[tid] += sh[tid + off];
        __syncthreads();
    }
    if (tid == 0) out[LOSS_OFF] = 0.25f * sh[0] / 8388608.f;

    float psum = 0.f;
    for (int k = 0; k < NBOOKS; ++k) {
        float h = 0.f;
        for (int c = tid; c < CODES; c += 256) {
            float p = (float)counts[(k << 10) + c] * (1.f / 32768.f);
            h += p * logf(p + 1e-10f);
        }
        __syncthreads();
        sh[tid] = h;
        __syncthreads();
        for (int off = 128; off; off >>= 1) {
            if (tid < off) sh[tid] += sh[tid + off];
            __syncthreads();
        }
        if (tid == 0) psum += expf(-sh[0]);
        __syncthreads();
    }
    if (tid == 0) out[PERP_OFF] = psum * (1.f / NBOOKS);
}

// ----------------------------------------------------------------
extern "C" void kernel_launch(void* const* d_in, const int* in_sizes, int n_in,
                              void* d_out, int out_size, void* d_ws, size_t ws_size,
                              hipStream_t stream) {
    const float* z   = (const float*)d_in[0];
    const float* emb = (const float*)d_in[1];
    float* out = (float*)d_out;
    char* ws = (char*)d_ws;

    float*  e2       = (float*)(ws + WS_E2);
    __bf16* ehi      = (__bf16*)(ws + WS_EHI);
    __bf16* elo      = (__bf16*)(ws + WS_ELO);
    int*    idxbuf   = (int*)(ws + WS_IDX);
    int*    counts   = (int*)(ws + WS_CNT);
    float*  partial  = (float*)(ws + WS_PART);
    int*    flagcnt  = (int*)(ws + WS_FLAGCNT);
    int*    flaglist = (int*)(ws + WS_FLAGS);

    hipMemsetAsync(counts, 0, CODES * NBOOKS * sizeof(int), stream);
    hipMemsetAsync(flagcnt, 0, sizeof(int), stream);

    k_e2<<<16, 256, 0, stream>>>(emb, e2);
    k_eprep<<<256, 256, 0, stream>>>(emb, ehi, elo);

    dim3 agrid(NPOS / 64, NBOOKS);
    k_argmin_mfma<<<agrid, 256, 0, stream>>>(z, e2, ehi, elo, idxbuf, flagcnt, flaglist);
    k_rescore<<<256, 256, 0, stream>>>(z, emb, e2, flagcnt, flaglist, idxbuf);

    dim3 qgrid(NPOS / 256, NBOOKS);
    k_quant<<<qgrid, 256, 0, stream>>>(z, emb, idxbuf, out, counts, partial);
    k_fin<<<1, 256, 0, stream>>>(counts, partial, out);
}

// Round 3
// 157.135 us; speedup vs baseline: 3.1542x; 1.3016x over previous
//
#include <hip/hip_runtime.h>

// Problem constants
#define NBOOKS 4
#define CODES  1024
#define DIM    64
#define NPOS   32768          // B*T*H*W
#define CCH    256            // NB*DIM (channel dim of z)
#define ENC_OFF  8388608
#define LOSS_OFF 8519680
#define PERP_OFF 8519681

// workspace byte offsets
#define WS_E2      0              // 4096 f32 = 16 KB
#define WS_EHI     16384          // 4096*64 bf16 = 512 KB  (holds hi of -2*e)
#define WS_ELO     540672         // 512 KB                  (holds lo of -2*e)
#define WS_IDX     1064960        // 131072 int = 512 KB
#define WS_CNT     1589248        // 4096 int = 16 KB
#define WS_PART    1605632        // 512 f32 = 2 KB
#define WS_FLAGCNT 1607680        // 1 int (pad 16)
#define WS_FLAGS   1607696        // 131072 int = 512 KB

#define MARGIN 0.03125f

typedef __bf16 bf16x8 __attribute__((ext_vector_type(8)));
typedef __bf16 bf16x4 __attribute__((ext_vector_type(4)));
typedef float  f32x4  __attribute__((ext_vector_type(4)));

// ------------------------------------------------- prep: e2, hi/lo(-2e), zeroing
__global__ void k_eprep2(const float* __restrict__ emb, float* __restrict__ e2,
                         __bf16* __restrict__ ehi, __bf16* __restrict__ elo,
                         int* __restrict__ counts, int* __restrict__ flagcnt) {
    int i = blockIdx.x * 256 + threadIdx.x;            // row 0..4095 = k*1024+c
    counts[i] = 0;
    if (i == 0) *flagcnt = 0;
    const float4* e = (const float4*)(emb + ((size_t)i << 6));
    __bf16* hp = ehi + ((size_t)i << 6);
    __bf16* lp = elo + ((size_t)i << 6);
    float s = 0.f;
#pragma unroll
    for (int j = 0; j < 16; ++j) {
        float4 v = e[j];
        s += v.x * v.x + v.y * v.y + v.z * v.z + v.w * v.w;
        bf16x4 hv, lv;
        float m;
        m = -2.f * v.x; hv[0] = (__bf16)m; lv[0] = (__bf16)(m - (float)hv[0]);
        m = -2.f * v.y; hv[1] = (__bf16)m; lv[1] = (__bf16)(m - (float)hv[1]);
        m = -2.f * v.z; hv[2] = (__bf16)m; lv[2] = (__bf16)(m - (float)hv[2]);
        m = -2.f * v.w; hv[3] = (__bf16)m; lv[3] = (__bf16)(m - (float)hv[3]);
        *(bf16x4*)&hp[j * 4] = hv;
        *(bf16x4*)&lp[j * 4] = lv;
    }
    e2[i] = s;
}

// ---------------------------------------------------------------- MFMA argmin
// Block: 64 positions x 1024 codes for one book. A = codes (pre-scaled -2e),
// B = positions, acc initialized with e2 -> acc IS the distance.
// X fragments hoisted to registers (loop-invariant across code tiles).
__global__ void __launch_bounds__(256) k_argmin_mfma(
        const float* __restrict__ z, const float* __restrict__ e2g,
        const __bf16* __restrict__ ehi, const __bf16* __restrict__ elo,
        int* __restrict__ idxbuf, int* __restrict__ flagcnt,
        int* __restrict__ flaglist) {
    __shared__ __attribute__((aligned(16))) __bf16 sXhi[4096];  // [d8][pos][8]
    __shared__ __attribute__((aligned(16))) __bf16 sXlo[4096];
    __shared__ float sm1[256], sm2[256];
    __shared__ int   si1[256];

    int tid = threadIdx.x;
    int wave = tid >> 6, lane = tid & 63;
    int lrow = lane >> 4, lcol = lane & 15;
    int k = blockIdx.y;
    int posbase = blockIdx.x * 64;
    int b = posbase >> 13, s0 = posbase & 8191;

    const float* zb = z + (((size_t)(b * CCH + k * DIM)) << 13) + s0;

    // ---- stage X tile: 64 pos x 64 dims -> bf16 hi/lo in LDS
    {
        int pos = tid & 63, dg = tid >> 6;
#pragma unroll
        for (int pass = 0; pass < 2; ++pass) {
            int d8 = dg + pass * 4;
            bf16x8 hv, lv;
#pragma unroll
            for (int j = 0; j < 8; ++j) {
                float f = zb[((size_t)(d8 * 8 + j) << 13) + pos];
                __bf16 h = (__bf16)f;
                hv[j] = h;
                lv[j] = (__bf16)(f - (float)h);
            }
            *(bf16x8*)&sXhi[(d8 * 64 + pos) * 8] = hv;
            *(bf16x8*)&sXlo[(d8 * 64 + pos) * 8] = lv;
        }
    }
    __syncthreads();

    // ---- hoist X fragments into registers (loop-invariant)
    bf16x8 xh0[4], xl0[4], xh1[4], xl1[4];
#pragma unroll
    for (int pt = 0; pt < 4; ++pt) {
        int xb = pt * 16 + lcol;
        xh0[pt] = *(const bf16x8*)&sXhi[(lrow * 64 + xb) * 8];
        xl0[pt] = *(const bf16x8*)&sXlo[(lrow * 64 + xb) * 8];
        xh1[pt] = *(const bf16x8*)&sXhi[((4 + lrow) * 64 + xb) * 8];
        xl1[pt] = *(const bf16x8*)&sXlo[((4 + lrow) * 64 + xb) * 8];
    }

    const __bf16* ehik = ehi + ((size_t)k << 16);
    const __bf16* elok = elo + ((size_t)k << 16);
    const float*  e2k  = e2g + (k << 10);

    float m1[4], m2[4];
    int   i1[4];
#pragma unroll
    for (int pt = 0; pt < 4; ++pt) { m1[pt] = 3.4e38f; m2[pt] = 3.4e38f; i1[pt] = 0; }

    for (int it = 0; it < 16; ++it) {
        int ct = wave * 16 + it;            // code-tile index 0..63
        int acode = ct * 16 + lcol;         // A-row this lane loads
        const __bf16* eph = ehik + acode * 64 + lrow * 8;
        const __bf16* epl = elok + acode * 64 + lrow * 8;
        bf16x8 eh0 = *(const bf16x8*)(eph);
        bf16x8 eh1 = *(const bf16x8*)(eph + 32);
        bf16x8 el0 = *(const bf16x8*)(epl);
        bf16x8 el1 = *(const bf16x8*)(epl + 32);
        f32x4 e2v = *(const f32x4*)(e2k + ct * 16 + lrow * 4);
        int ibase = it * 16;                // + wave*256 + lrow*4 added at end

#pragma unroll
        for (int pt = 0; pt < 4; ++pt) {
            f32x4 acc = e2v;                // fold +e2 into accumulator init
            acc = __builtin_amdgcn_mfma_f32_16x16x32_bf16(eh0, xh0[pt], acc, 0, 0, 0);
            acc = __builtin_amdgcn_mfma_f32_16x16x32_bf16(eh0, xl0[pt], acc, 0, 0, 0);
            acc = __builtin_amdgcn_mfma_f32_16x16x32_bf16(el0, xh0[pt], acc, 0, 0, 0);
            acc = __builtin_amdgcn_mfma_f32_16x16x32_bf16(eh1, xh1[pt], acc, 0, 0, 0);
            acc = __builtin_amdgcn_mfma_f32_16x16x32_bf16(eh1, xl1[pt], acc, 0, 0, 0);
            acc = __builtin_amdgcn_mfma_f32_16x16x32_bf16(el1, xh1[pt], acc, 0, 0, 0);
#pragma unroll
            for (int r = 0; r < 4; ++r) {
                float dist = acc[r];
                // 5-op track: m2 = min(m2, max(dist, m1_old)); m1 = min(m1, dist)
                float mx = fmaxf(dist, m1[pt]);
                bool lt = dist < m1[pt];
                m2[pt] = fminf(m2[pt], mx);
                i1[pt] = lt ? (ibase + r) : i1[pt];
                m1[pt] = fminf(m1[pt], dist);
            }
        }
    }
    int iadd = wave * 256 + lrow * 4;
#pragma unroll
    for (int pt = 0; pt < 4; ++pt) i1[pt] += iadd;

    // ---- merge across lane-groups (4 lanes hold same position)
#pragma unroll
    for (int off = 16; off < 64; off <<= 1) {
#pragma unroll
        for (int pt = 0; pt < 4; ++pt) {
            float om1 = __shfl_xor(m1[pt], off);
            float om2 = __shfl_xor(m2[pt], off);
            int   oi  = __shfl_xor(i1[pt], off);
            bool take = (om1 < m1[pt]) || (om1 == m1[pt] && oi < i1[pt]);
            float loser = take ? m1[pt] : om1;
            m2[pt] = fminf(fminf(m2[pt], om2), loser);
            m1[pt] = take ? om1 : m1[pt];
            i1[pt] = take ? oi  : i1[pt];
        }
    }
    if (lane < 16) {
#pragma unroll
        for (int pt = 0; pt < 4; ++pt) {
            int p = pt * 16 + lane;
            sm1[wave * 64 + p] = m1[pt];
            sm2[wave * 64 + p] = m2[pt];
            si1[wave * 64 + p] = i1[pt];
        }
    }
    __syncthreads();

    // ---- merge across 4 waves, write idx, flag near-ties
    if (tid < 64) {
        float a1 = sm1[tid], a2 = sm2[tid];
        int   ai = si1[tid];
#pragma unroll
        for (int w = 1; w < 4; ++w) {
            float b1 = sm1[w * 64 + tid], b2 = sm2[w * 64 + tid];
            int   bi = si1[w * 64 + tid];
            bool take = (b1 < a1) || (b1 == a1 && bi < ai);
            float loser = take ? a1 : b1;
            a2 = fminf(fminf(a2, b2), loser);
            if (take) { a1 = b1; ai = bi; }
        }
        int n = posbase + tid;
        idxbuf[(k << 15) + n] = ai;
        if (a2 - a1 < MARGIN) {
            int slot = atomicAdd(flagcnt, 1);
            flaglist[slot] = (k << 15) + n;
        }
    }
}

// ---------------------------------------------------------------- exact rescore
__global__ void __launch_bounds__(256) k_rescore(
        const float* __restrict__ z, const float* __restrict__ emb,
        const float* __restrict__ e2g, const int* __restrict__ flagcnt,
        const int* __restrict__ flaglist, int* __restrict__ idxbuf) {
    __shared__ float xsh[64];
    __shared__ float rm[256];
    __shared__ int   ri[256];
    int tid = threadIdx.x;
    int nf = *flagcnt;
    for (int e = blockIdx.x; e < nf; e += gridDim.x) {
        int gp = flaglist[e];
        int k = gp >> 15, n = gp & 32767;
        int b = n >> 13, s = n & 8191;
        if (tid < 64)
            xsh[tid] = z[(((size_t)(b * CCH + k * DIM + tid)) << 13) + s];
        __syncthreads();
        float best = 3.4e38f;
        int   bi = 0;
        for (int c = tid; c < CODES; c += 256) {
            const float* ev = emb + ((size_t)k << 16) + ((size_t)c << 6);
            float a0 = 0.f, a1 = 0.f, a2 = 0.f, a3 = 0.f;
#pragma unroll
            for (int d = 0; d < DIM; d += 4) {
                a0 = fmaf(xsh[d + 0], ev[d + 0], a0);
                a1 = fmaf(xsh[d + 1], ev[d + 1], a1);
                a2 = fmaf(xsh[d + 2], ev[d + 2], a2);
                a3 = fmaf(xsh[d + 3], ev[d + 3], a3);
            }
            float dot = (a0 + a1) + (a2 + a3);
            float dist = fmaf(-2.f, dot, e2g[(k << 10) + c]);
            if (dist < best) { best = dist; bi = c; }
        }
        rm[tid] = best; ri[tid] = bi;
        __syncthreads();
        for (int off = 128; off; off >>= 1) {
            if (tid < off) {
                float bv = rm[tid + off]; int bx = ri[tid + off];
                if (bv < rm[tid] || (bv == rm[tid] && bx < ri[tid])) {
                    rm[tid] = bv; ri[tid] = bx;
                }
            }
            __syncthreads();
        }
        if (tid == 0) idxbuf[(k << 15) + n] = ri[0];
        __syncthreads();
    }
}

// ---------------------------------------------------------------- gather+loss
// 2 consecutive positions per thread -> float2 (512B/wave) loads & stores.
__global__ void __launch_bounds__(256) k_quant(
        const float* __restrict__ z, const float* __restrict__ emb,
        const int* __restrict__ idxbuf, float* __restrict__ out,
        int* __restrict__ counts, float* __restrict__ partial) {
    int tid = threadIdx.x;
    int p = blockIdx.x * 256 + tid;       // pair index
    int n0 = p * 2;
    int k = blockIdx.y;
    int b = n0 >> 13;
    int s = n0 & 8191;

    int bi0 = idxbuf[(k << 15) + n0];
    int bi1 = idxbuf[(k << 15) + n0 + 1];
    const float4* e0 = (const float4*)(emb + ((size_t)k << 16) + ((size_t)bi0 << 6));
    const float4* e1 = (const float4*)(emb + ((size_t)k << 16) + ((size_t)bi1 << 6));
    size_t base = (((size_t)(b * CCH + k * DIM)) << 13) + s;
    const float2* zp = (const float2*)(z + base);
    float2* qp = (float2*)(out + base);

    float sq = 0.f;
#pragma unroll
    for (int j = 0; j < 16; ++j) {
        float4 q40 = e0[j];
        float4 q41 = e1[j];
        int d = j * 4;
        float2 z0 = zp[(size_t)(d + 0) << 12];
        float2 z1 = zp[(size_t)(d + 1) << 12];
        float2 z2 = zp[(size_t)(d + 2) << 12];
        float2 z3 = zp[(size_t)(d + 3) << 12];
        float2 o0 = {q40.x, q41.x};
        float2 o1 = {q40.y, q41.y};
        float2 o2 = {q40.z, q41.z};
        float2 o3 = {q40.w, q41.w};
        qp[(size_t)(d + 0) << 12] = o0;
        qp[(size_t)(d + 1) << 12] = o1;
        qp[(size_t)(d + 2) << 12] = o2;
        qp[(size_t)(d + 3) << 12] = o3;
        float u;
        u = z0.x - o0.x; sq = fmaf(u, u, sq);
        u = z0.y - o0.y; sq = fmaf(u, u, sq);
        u = z1.x - o1.x; sq = fmaf(u, u, sq);
        u = z1.y - o1.y; sq = fmaf(u, u, sq);
        u = z2.x - o2.x; sq = fmaf(u, u, sq);
        u = z2.y - o2.y; sq = fmaf(u, u, sq);
        u = z3.x - o3.x; sq = fmaf(u, u, sq);
        u = z3.y - o3.y; sq = fmaf(u, u, sq);
    }

    out[ENC_OFF + (size_t)n0 * NBOOKS + k] = (float)bi0;
    out[ENC_OFF + (size_t)(n0 + 1) * NBOOKS + k] = (float)bi1;
    atomicAdd(&counts[(k << 10) + bi0], 1);
    atomicAdd(&counts[(k << 10) + bi1], 1);

    for (int off = 32; off; off >>= 1) sq += __shfl_down(sq, off, 64);
    __shared__ float red[4];
    if ((tid & 63) == 0) red[tid >> 6] = sq;
    __syncthreads();
    if (tid == 0)
        partial[blockIdx.y * gridDim.x + blockIdx.x] = (red[0] + red[1]) + (red[2] + red[3]);
}

// ---------------------------------------------------------------- finalize
__global__ void __launch_bounds__(256) k_fin(
        const int* __restrict__ counts, const float* __restrict__ partial,
        float* __restrict__ out) {
    __shared__ float sh[256];
    int tid = threadIdx.x;

    sh[tid] = partial[tid];                 // 256 partials (64 blocks x 4 books)
    __syncthreads();
    for (int off = 128; off; off >>= 1) {
        if (tid < off) sh[tid] += sh[tid + off];
        __syncthreads();
    }
    if (tid == 0) out[LOSS_OFF] = 0.25f * sh[0] / 8388608.f;

    float psum = 0.f;
    for (int k = 0; k < NBOOKS; ++k) {
        float h = 0.f;
        for (int c = tid; c < CODES; c += 256) {
            float p = (float)counts[(k << 10) + c] * (1.f / 32768.f);
            h += p * logf(p + 1e-10f);
        }
        __syncthreads();
        sh[tid] = h;
        __syncthreads();
        for (int off = 128; off; off >>= 1) {
            if (tid < off) sh[tid] += sh[tid + off];
            __syncthreads();
        }
        if (tid == 0) psum += expf(-sh[0]);
        __syncthreads();
    }
    if (tid == 0) out[PERP_OFF] = psum * (1.f / NBOOKS);
}

// ----------------------------------------------------------------
extern "C" void kernel_launch(void* const* d_in, const int* in_sizes, int n_in,
                              void* d_out, int out_size, void* d_ws, size_t ws_size,
                              hipStream_t stream) {
    const float* z   = (const float*)d_in[0];
    const float* emb = (const float*)d_in[1];
    float* out = (float*)d_out;
    char* ws = (char*)d_ws;

    float*  e2       = (float*)(ws + WS_E2);
    __bf16* ehi      = (__bf16*)(ws + WS_EHI);
    __bf16* elo      = (__bf16*)(ws + WS_ELO);
    int*    idxbuf   = (int*)(ws + WS_IDX);
    int*    counts   = (int*)(ws + WS_CNT);
    float*  partial  = (float*)(ws + WS_PART);
    int*    flagcnt  = (int*)(ws + WS_FLAGCNT);
    int*    flaglist = (int*)(ws + WS_FLAGS);

    k_eprep2<<<16, 256, 0, stream>>>(emb, e2, ehi, elo, counts, flagcnt);

    dim3 agrid(NPOS / 64, NBOOKS);
    k_argmin_mfma<<<agrid, 256, 0, stream>>>(z, e2, ehi, elo, idxbuf, flagcnt, flaglist);
    k_rescore<<<2048, 256, 0, stream>>>(z, emb, e2, flagcnt, flaglist, idxbuf);

    dim3 qgrid(NPOS / 512, NBOOKS);
    k_quant<<<qgrid, 256, 0, stream>>>(z, emb, idxbuf, out, counts, partial);
    k_fin<<<1, 256, 0, stream>>>(counts, partial, out);
}

// Round 4
// 140.675 us; speedup vs baseline: 3.5232x; 1.1170x over previous
//
#include <hip/hip_runtime.h>

// Problem constants
#define NBOOKS 4
#define CODES  1024
#define DIM    64
#define NPOS   32768          // B*T*H*W
#define CCH    256            // NB*DIM (channel dim of z)
#define ENC_OFF  8388608
#define LOSS_OFF 8519680
#define PERP_OFF 8519681

// workspace byte offsets
#define WS_E2      0              // 4096 f32 (holds 512 + ||e||^2)
#define WS_EHI     16384          // 4096*64 f16 = 512 KB  (hi of -2*e)
#define WS_ELO     540672         // 512 KB                 (lo of -2*e)
#define WS_IDX     1064960        // 131072 int
#define WS_CNT     1589248        // 4096 int
#define WS_PART    1605632        // 128 f32
#define WS_FLAGCNT 1607680        // 1 int
#define WS_FLAGS   1607696        // 131072 int

#define MARGIN 0.015625f
#define DBIAS  512.0f

typedef _Float16 f16x8 __attribute__((ext_vector_type(8)));
typedef _Float16 f16x4 __attribute__((ext_vector_type(4)));
typedef float    f32x4 __attribute__((ext_vector_type(4)));

// ------------------------------------------- prep: e2+bias, hi/lo f16(-2e), zeroing
__global__ void k_eprep2(const float* __restrict__ emb, float* __restrict__ e2,
                         _Float16* __restrict__ ehi, _Float16* __restrict__ elo,
                         int* __restrict__ counts, int* __restrict__ flagcnt) {
    int i = blockIdx.x * 256 + threadIdx.x;            // row 0..4095 = k*1024+c
    counts[i] = 0;
    if (i == 0) *flagcnt = 0;
    const float4* e = (const float4*)(emb + ((size_t)i << 6));
    _Float16* hp = ehi + ((size_t)i << 6);
    _Float16* lp = elo + ((size_t)i << 6);
    float s = 0.f;
#pragma unroll
    for (int j = 0; j < 16; ++j) {
        float4 v = e[j];
        s += v.x * v.x + v.y * v.y + v.z * v.z + v.w * v.w;
        f16x4 hv, lv;
        float m;
        m = -2.f * v.x; hv[0] = (_Float16)m; lv[0] = (_Float16)(m - (float)hv[0]);
        m = -2.f * v.y; hv[1] = (_Float16)m; lv[1] = (_Float16)(m - (float)hv[1]);
        m = -2.f * v.z; hv[2] = (_Float16)m; lv[2] = (_Float16)(m - (float)hv[2]);
        m = -2.f * v.w; hv[3] = (_Float16)m; lv[3] = (_Float16)(m - (float)hv[3]);
        *(f16x4*)&hp[j * 4] = hv;
        *(f16x4*)&lp[j * 4] = lv;
    }
    e2[i] = s + DBIAS;   // bias makes computed distances strictly positive
}

// ---------------------------------------------------------------- MFMA argmin
// Block: 64 positions x 1024 codes for one book. A = codes (f16 hi/lo of -2e),
// B = positions. acc init = e2+512 -> acc IS (biased, positive) distance.
// Packed-key tracking: key = (dist_bits & ~63) | (it*4+r); uint min gives
// argmin with exact first-min tie-break. Near-ties rescored exactly in fp32.
__global__ void __launch_bounds__(256, 3) k_argmin_mfma(
        const float* __restrict__ z, const float* __restrict__ e2g,
        const _Float16* __restrict__ ehi, const _Float16* __restrict__ elo,
        int* __restrict__ idxbuf, int* __restrict__ flagcnt,
        int* __restrict__ flaglist) {
    __shared__ __attribute__((aligned(16))) _Float16 sXhi[4096];  // [d8][pos][8]
    __shared__ __attribute__((aligned(16))) _Float16 sXlo[4096];
    __shared__ float sm1[256], sm2[256];
    __shared__ int   si1[256];

    int tid = threadIdx.x;
    int wave = tid >> 6, lane = tid & 63;
    int lrow = lane >> 4, lcol = lane & 15;
    int k = blockIdx.y;
    int posbase = blockIdx.x * 64;
    int b = posbase >> 13, s0 = posbase & 8191;

    const float* zb = z + (((size_t)(b * CCH + k * DIM)) << 13) + s0;

    // ---- stage X tile: 64 pos x 64 dims -> f16 hi/lo in LDS
    {
        int pos = tid & 63, dg = tid >> 6;
#pragma unroll
        for (int pass = 0; pass < 2; ++pass) {
            int d8 = dg + pass * 4;
            f16x8 hv, lv;
#pragma unroll
            for (int j = 0; j < 8; ++j) {
                float f = zb[((size_t)(d8 * 8 + j) << 13) + pos];
                _Float16 h = (_Float16)f;
                hv[j] = h;
                lv[j] = (_Float16)(f - (float)h);
            }
            *(f16x8*)&sXhi[(d8 * 64 + pos) * 8] = hv;
            *(f16x8*)&sXlo[(d8 * 64 + pos) * 8] = lv;
        }
    }
    __syncthreads();

    // ---- hoist X fragments into registers (loop-invariant, 64 VGPR)
    f16x8 xh0[4], xl0[4], xh1[4], xl1[4];
#pragma unroll
    for (int pt = 0; pt < 4; ++pt) {
        int xb = pt * 16 + lcol;
        xh0[pt] = *(const f16x8*)&sXhi[(lrow * 64 + xb) * 8];
        xl0[pt] = *(const f16x8*)&sXlo[(lrow * 64 + xb) * 8];
        xh1[pt] = *(const f16x8*)&sXhi[((4 + lrow) * 64 + xb) * 8];
        xl1[pt] = *(const f16x8*)&sXlo[((4 + lrow) * 64 + xb) * 8];
    }

    const _Float16* ehik = ehi + ((size_t)k << 16);
    const _Float16* elok = elo + ((size_t)k << 16);
    const float*    e2k  = e2g + (k << 10);

    unsigned int m1[4], m2[4];
#pragma unroll
    for (int pt = 0; pt < 4; ++pt) { m1[pt] = 0x7F7FFFFFu; m2[pt] = 0x7F7FFFFFu; }

    for (int it = 0; it < 16; ++it) {
        int ct = wave * 16 + it;            // code-tile index 0..63
        int acode = ct * 16 + lcol;         // A-row this lane loads
        const _Float16* eph = ehik + acode * 64 + lrow * 8;
        const _Float16* epl = elok + acode * 64 + lrow * 8;
        f16x8 eh0 = *(const f16x8*)(eph);
        f16x8 eh1 = *(const f16x8*)(eph + 32);
        f16x8 el0 = *(const f16x8*)(epl);
        f16x8 el1 = *(const f16x8*)(epl + 32);
        f32x4 e2v = *(const f32x4*)(e2k + ct * 16 + lrow * 4);
        unsigned int vidx = (unsigned int)(it * 4);

#pragma unroll
        for (int pt = 0; pt < 4; ++pt) {
            f32x4 acc = e2v;                // +e2+bias folded into init
            acc = __builtin_amdgcn_mfma_f32_16x16x32_f16(eh0, xh0[pt], acc, 0, 0, 0);
            acc = __builtin_amdgcn_mfma_f32_16x16x32_f16(eh0, xl0[pt], acc, 0, 0, 0);
            acc = __builtin_amdgcn_mfma_f32_16x16x32_f16(el0, xh0[pt], acc, 0, 0, 0);
            acc = __builtin_amdgcn_mfma_f32_16x16x32_f16(eh1, xh1[pt], acc, 0, 0, 0);
            acc = __builtin_amdgcn_mfma_f32_16x16x32_f16(eh1, xl1[pt], acc, 0, 0, 0);
            acc = __builtin_amdgcn_mfma_f32_16x16x32_f16(el1, xh1[pt], acc, 0, 0, 0);
#pragma unroll
            for (int r = 0; r < 4; ++r) {
                unsigned int key = (__float_as_uint(acc[r]) & 0xFFFFFFC0u)
                                 | (vidx + (unsigned int)r);
                unsigned int mx = key > m1[pt] ? key : m1[pt];
                m2[pt] = m2[pt] < mx ? m2[pt] : mx;
                m1[pt] = m1[pt] < key ? m1[pt] : key;
            }
        }
    }

    // ---- unpack keys
    float f1[4], f2[4];
    int   i1[4];
#pragma unroll
    for (int pt = 0; pt < 4; ++pt) {
        unsigned int lm = m1[pt] & 63u;
        i1[pt] = wave * 256 + (int)(lm >> 2) * 16 + lrow * 4 + (int)(lm & 3u);
        f1[pt] = __uint_as_float(m1[pt] & 0xFFFFFFC0u);
        f2[pt] = __uint_as_float(m2[pt] & 0xFFFFFFC0u);
    }

    // ---- merge across lane-groups (4 lanes hold same position)
#pragma unroll
    for (int off = 16; off < 64; off <<= 1) {
#pragma unroll
        for (int pt = 0; pt < 4; ++pt) {
            float om1 = __shfl_xor(f1[pt], off);
            float om2 = __shfl_xor(f2[pt], off);
            int   oi  = __shfl_xor(i1[pt], off);
            bool take = (om1 < f1[pt]) || (om1 == f1[pt] && oi < i1[pt]);
            float loser = take ? f1[pt] : om1;
            f2[pt] = fminf(fminf(f2[pt], om2), loser);
            f1[pt] = take ? om1 : f1[pt];
            i1[pt] = take ? oi  : i1[pt];
        }
    }
    if (lane < 16) {
#pragma unroll
        for (int pt = 0; pt < 4; ++pt) {
            int p = pt * 16 + lane;
            sm1[wave * 64 + p] = f1[pt];
            sm2[wave * 64 + p] = f2[pt];
            si1[wave * 64 + p] = i1[pt];
        }
    }
    __syncthreads();

    // ---- merge across 4 waves, write idx, flag near-ties
    if (tid < 64) {
        float a1 = sm1[tid], a2 = sm2[tid];
        int   ai = si1[tid];
#pragma unroll
        for (int w = 1; w < 4; ++w) {
            float b1 = sm1[w * 64 + tid], b2 = sm2[w * 64 + tid];
            int   bi = si1[w * 64 + tid];
            bool take = (b1 < a1) || (b1 == a1 && bi < ai);
            float loser = take ? a1 : b1;
            a2 = fminf(fminf(a2, b2), loser);
            if (take) { a1 = b1; ai = bi; }
        }
        int n = posbase + tid;
        idxbuf[(k << 15) + n] = ai;
        if (a2 - a1 < MARGIN) {
            int slot = atomicAdd(flagcnt, 1);
            flaglist[slot] = (k << 15) + n;
        }
    }
}

// ---------------------------------------------------------------- exact rescore
__global__ void __launch_bounds__(256) k_rescore(
        const float* __restrict__ z, const float* __restrict__ emb,
        const float* __restrict__ e2g, const int* __restrict__ flagcnt,
        const int* __restrict__ flaglist, int* __restrict__ idxbuf) {
    __shared__ float xsh[64];
    __shared__ float rm[256];
    __shared__ int   ri[256];
    int tid = threadIdx.x;
    int nf = *flagcnt;
    for (int e = blockIdx.x; e < nf; e += gridDim.x) {
        int gp = flaglist[e];
        int k = gp >> 15, n = gp & 32767;
        int b = n >> 13, s = n & 8191;
        if (tid < 64)
            xsh[tid] = z[(((size_t)(b * CCH + k * DIM + tid)) << 13) + s];
        __syncthreads();
        float best = 3.4e38f;
        int   bi = 0;
        for (int c = tid; c < CODES; c += 256) {
            const float* ev = emb + ((size_t)k << 16) + ((size_t)c << 6);
            float a0 = 0.f, a1 = 0.f, a2 = 0.f, a3 = 0.f;
#pragma unroll
            for (int d = 0; d < DIM; d += 4) {
                a0 = fmaf(xsh[d + 0], ev[d + 0], a0);
                a1 = fmaf(xsh[d + 1], ev[d + 1], a1);
                a2 = fmaf(xsh[d + 2], ev[d + 2], a2);
                a3 = fmaf(xsh[d + 3], ev[d + 3], a3);
            }
            float dot = (a0 + a1) + (a2 + a3);
            // e2g carries +512 bias: constant shift, argmin unaffected
            float dist = fmaf(-2.f, dot, e2g[(k << 10) + c]);
            if (dist < best) { best = dist; bi = c; }
        }
        rm[tid] = best; ri[tid] = bi;
        __syncthreads();
        for (int off = 128; off; off >>= 1) {
            if (tid < off) {
                float bv = rm[tid + off]; int bx = ri[tid + off];
                if (bv < rm[tid] || (bv == rm[tid] && bx < ri[tid])) {
                    rm[tid] = bv; ri[tid] = bx;
                }
            }
            __syncthreads();
        }
        if (tid == 0) idxbuf[(k << 15) + n] = ri[0];
        __syncthreads();
    }
}

// ---------------------------------------------------------------- gather+loss
// 4 consecutive positions per thread -> float4 z loads / q stores.
__global__ void __launch_bounds__(256) k_quant(
        const float* __restrict__ z, const float* __restrict__ emb,
        const int* __restrict__ idxbuf, float* __restrict__ out,
        int* __restrict__ counts, float* __restrict__ partial) {
    int tid = threadIdx.x;
    int q = blockIdx.x * 256 + tid;       // quad index
    int n0 = q * 4;
    int k = blockIdx.y;
    int b = n0 >> 13;
    int s = n0 & 8191;

    int4 bi = *(const int4*)&idxbuf[(k << 15) + n0];
    const f32x4* e0 = (const f32x4*)(emb + ((size_t)k << 16) + ((size_t)bi.x << 6));
    const f32x4* e1 = (const f32x4*)(emb + ((size_t)k << 16) + ((size_t)bi.y << 6));
    const f32x4* e2 = (const f32x4*)(emb + ((size_t)k << 16) + ((size_t)bi.z << 6));
    const f32x4* e3 = (const f32x4*)(emb + ((size_t)k << 16) + ((size_t)bi.w << 6));
    size_t base = (((size_t)(b * CCH + k * DIM)) << 13) + s;

    float sq = 0.f;
#pragma unroll
    for (int j = 0; j < 16; ++j) {
        f32x4 q0 = e0[j], q1 = e1[j], q2 = e2[j], q3 = e3[j];
#pragma unroll
        for (int i = 0; i < 4; ++i) {
            int d = j * 4 + i;
            f32x4 zv = *(const f32x4*)(z + base + ((size_t)d << 13));
            f32x4 ov = {q0[i], q1[i], q2[i], q3[i]};
            *(f32x4*)(out + base + ((size_t)d << 13)) = ov;
            f32x4 df = zv - ov;
            sq = fmaf(df[0], df[0], sq);
            sq = fmaf(df[1], df[1], sq);
            sq = fmaf(df[2], df[2], sq);
            sq = fmaf(df[3], df[3], sq);
        }
    }

    out[ENC_OFF + (size_t)(n0 + 0) * NBOOKS + k] = (float)bi.x;
    out[ENC_OFF + (size_t)(n0 + 1) * NBOOKS + k] = (float)bi.y;
    out[ENC_OFF + (size_t)(n0 + 2) * NBOOKS + k] = (float)bi.z;
    out[ENC_OFF + (size_t)(n0 + 3) * NBOOKS + k] = (float)bi.w;
    atomicAdd(&counts[(k << 10) + bi.x], 1);
    atomicAdd(&counts[(k << 10) + bi.y], 1);
    atomicAdd(&counts[(k << 10) + bi.z], 1);
    atomicAdd(&counts[(k << 10) + bi.w], 1);

    for (int off = 32; off; off >>= 1) sq += __shfl_down(sq, off, 64);
    __shared__ float red[4];
    if ((tid & 63) == 0) red[tid >> 6] = sq;
    __syncthreads();
    if (tid == 0)
        partial[blockIdx.y * gridDim.x + blockIdx.x] = (red[0] + red[1]) + (red[2] + red[3]);
}

// ---------------------------------------------------------------- finalize
__global__ void __launch_bounds__(256) k_fin(
        const int* __restrict__ counts, const float* __restrict__ partial,
        float* __restrict__ out) {
    __shared__ float sh[256];
    int tid = threadIdx.x;

    sh[tid] = tid < 128 ? partial[tid] : 0.f;   // 32 blocks x 4 books
    __syncthreads();
    for (int off = 128; off; off >>= 1) {
        if (tid < off) sh[tid] += sh[tid + off];
        __syncthreads();
    }
    if (tid == 0) out[LOSS_OFF] = 0.25f * sh[0] / 8388608.f;

    float psum = 0.f;
    for (int k = 0; k < NBOOKS; ++k) {
        float h = 0.f;
        for (int c = tid; c < CODES; c += 256) {
            float p = (float)counts[(k << 10) + c] * (1.f / 32768.f);
            h += p * logf(p + 1e-10f);
        }
        __syncthreads();
        sh[tid] = h;
        __syncthreads();
        for (int off = 128; off; off >>= 1) {
            if (tid < off) sh[tid] += sh[tid + off];
            __syncthreads();
        }
        if (tid == 0) psum += expf(-sh[0]);
        __syncthreads();
    }
    if (tid == 0) out[PERP_OFF] = psum * (1.f / NBOOKS);
}

// ----------------------------------------------------------------
extern "C" void kernel_launch(void* const* d_in, const int* in_sizes, int n_in,
                              void* d_out, int out_size, void* d_ws, size_t ws_size,
                              hipStream_t stream) {
    const float* z   = (const float*)d_in[0];
    const float* emb = (const float*)d_in[1];
    float* out = (float*)d_out;
    char* ws = (char*)d_ws;

    float*    e2       = (float*)(ws + WS_E2);
    _Float16* ehi      = (_Float16*)(ws + WS_EHI);
    _Float16* elo      = (_Float16*)(ws + WS_ELO);
    int*      idxbuf   = (int*)(ws + WS_IDX);
    int*      counts   = (int*)(ws + WS_CNT);
    float*    partial  = (float*)(ws + WS_PART);
    int*      flagcnt  = (int*)(ws + WS_FLAGCNT);
    int*      flaglist = (int*)(ws + WS_FLAGS);

    k_eprep2<<<16, 256, 0, stream>>>(emb, e2, ehi, elo, counts, flagcnt);

    dim3 agrid(NPOS / 64, NBOOKS);
    k_argmin_mfma<<<agrid, 256, 0, stream>>>(z, e2, ehi, elo, idxbuf, flagcnt, flaglist);
    k_rescore<<<1024, 256, 0, stream>>>(z, emb, e2, flagcnt, flaglist, idxbuf);

    dim3 qgrid(NPOS / 1024, NBOOKS);
    k_quant<<<qgrid, 256, 0, stream>>>(z, emb, idxbuf, out, counts, partial);
    k_fin<<<1, 256, 0, stream>>>(counts, partial, out);
}

// Round 5
// 138.075 us; speedup vs baseline: 3.5896x; 1.0188x over previous
//
#include <hip/hip_runtime.h>

// Problem constants
#define NBOOKS 4
#define CODES  1024
#define DIM    64
#define NPOS   32768          // B*T*H*W
#define CCH    256            // NB*DIM (channel dim of z)
#define ENC_OFF  8388608
#define LOSS_OFF 8519680
#define PERP_OFF 8519681

// workspace byte offsets
#define WS_E2      0              // 4096 f32 (holds 512 + ||e||^2)
#define WS_EHI     16384          // 4096*64 f16 = 512 KB  (hi of -2*e)
#define WS_ELO     540672         // 512 KB                 (lo of -2*e)
#define WS_IDX     1064960        // 131072 int
#define WS_CNT     1589248        // 4096 int
#define WS_PART    1605632        // 128 f32
#define WS_FLAGCNT 1607680        // 1 int
#define WS_FLAGS   1607696        // 131072 int

#define MARGIN 0.015625f
#define DBIAS  512.0f

typedef _Float16 f16x8 __attribute__((ext_vector_type(8)));
typedef _Float16 f16x4 __attribute__((ext_vector_type(4)));
typedef float    f32x4 __attribute__((ext_vector_type(4)));

// ------------------------------------------- prep: e2+bias, hi/lo f16(-2e), zeroing
__global__ void k_eprep2(const float* __restrict__ emb, float* __restrict__ e2,
                         _Float16* __restrict__ ehi, _Float16* __restrict__ elo,
                         int* __restrict__ counts, int* __restrict__ flagcnt) {
    int i = blockIdx.x * 256 + threadIdx.x;            // row 0..4095 = k*1024+c
    counts[i] = 0;
    if (i == 0) *flagcnt = 0;
    const float4* e = (const float4*)(emb + ((size_t)i << 6));
    _Float16* hp = ehi + ((size_t)i << 6);
    _Float16* lp = elo + ((size_t)i << 6);
    float s = 0.f;
#pragma unroll
    for (int j = 0; j < 16; ++j) {
        float4 v = e[j];
        s += v.x * v.x + v.y * v.y + v.z * v.z + v.w * v.w;
        f16x4 hv, lv;
        float m;
        m = -2.f * v.x; hv[0] = (_Float16)m; lv[0] = (_Float16)(m - (float)hv[0]);
        m = -2.f * v.y; hv[1] = (_Float16)m; lv[1] = (_Float16)(m - (float)hv[1]);
        m = -2.f * v.z; hv[2] = (_Float16)m; lv[2] = (_Float16)(m - (float)hv[2]);
        m = -2.f * v.w; hv[3] = (_Float16)m; lv[3] = (_Float16)(m - (float)hv[3]);
        *(f16x4*)&hp[j * 4] = hv;
        *(f16x4*)&lp[j * 4] = lv;
    }
    e2[i] = s + DBIAS;   // bias makes computed distances strictly positive
}

// ---------------------------------------------------------------- MFMA argmin
// Block: 64 positions x 1024 codes for one book. A = codes (f16 hi/lo of -2e),
// B = positions. acc init = e2+512 -> acc IS (biased, positive) distance.
// X fragments register-pinned via opaque asm (defeats LDS rematerialization);
// E stream software-pipelined 1 deep to hide L2 latency.
__global__ void __launch_bounds__(256, 3) k_argmin_mfma(
        const float* __restrict__ z, const float* __restrict__ e2g,
        const _Float16* __restrict__ ehi, const _Float16* __restrict__ elo,
        int* __restrict__ idxbuf, int* __restrict__ flagcnt,
        int* __restrict__ flaglist) {
    __shared__ __attribute__((aligned(16))) _Float16 sXhi[4096];  // [d8][pos][8]
    __shared__ __attribute__((aligned(16))) _Float16 sXlo[4096];
    __shared__ float sm1[256], sm2[256];
    __shared__ int   si1[256];

    int tid = threadIdx.x;
    int wave = tid >> 6, lane = tid & 63;
    int lrow = lane >> 4, lcol = lane & 15;
    int k = blockIdx.y;
    int posbase = blockIdx.x * 64;
    int b = posbase >> 13, s0 = posbase & 8191;

    const float* zb = z + (((size_t)(b * CCH + k * DIM)) << 13) + s0;

    // ---- stage X tile: 64 pos x 64 dims -> f16 hi/lo in LDS
    {
        int pos = tid & 63, dg = tid >> 6;
#pragma unroll
        for (int pass = 0; pass < 2; ++pass) {
            int d8 = dg + pass * 4;
            f16x8 hv, lv;
#pragma unroll
            for (int j = 0; j < 8; ++j) {
                float f = zb[((size_t)(d8 * 8 + j) << 13) + pos];
                _Float16 h = (_Float16)f;
                hv[j] = h;
                lv[j] = (_Float16)(f - (float)h);
            }
            *(f16x8*)&sXhi[(d8 * 64 + pos) * 8] = hv;
            *(f16x8*)&sXlo[(d8 * 64 + pos) * 8] = lv;
        }
    }
    __syncthreads();

    // ---- hoist X fragments into registers and PIN them (opaque asm blocks
    //      the compiler's LDS-rematerialization)
    f32x4 Xh0[4], Xl0[4], Xh1[4], Xl1[4];
#pragma unroll
    for (int pt = 0; pt < 4; ++pt) {
        int xb = pt * 16 + lcol;
        Xh0[pt] = *(const f32x4*)&sXhi[(lrow * 64 + xb) * 8];
        Xl0[pt] = *(const f32x4*)&sXlo[(lrow * 64 + xb) * 8];
        Xh1[pt] = *(const f32x4*)&sXhi[((4 + lrow) * 64 + xb) * 8];
        Xl1[pt] = *(const f32x4*)&sXlo[((4 + lrow) * 64 + xb) * 8];
        asm volatile("" : "+v"(Xh0[pt]), "+v"(Xl0[pt]), "+v"(Xh1[pt]), "+v"(Xl1[pt]));
    }

    const _Float16* ehik = ehi + ((size_t)k << 16);
    const _Float16* elok = elo + ((size_t)k << 16);
    const float*    e2k  = e2g + (k << 10);

    // per-wave E stream base: acode(it) = wave*256 + it*16 + lcol
    int acode0 = wave * 256 + lcol;
    const _Float16* ephb = ehik + (size_t)acode0 * 64 + lrow * 8;
    const _Float16* eplb = elok + (size_t)acode0 * 64 + lrow * 8;
    const float*    e2b  = e2k + wave * 256 + lrow * 4;

    f16x8 ceh0 = *(const f16x8*)(ephb);
    f16x8 ceh1 = *(const f16x8*)(ephb + 32);
    f16x8 cel0 = *(const f16x8*)(eplb);
    f16x8 cel1 = *(const f16x8*)(eplb + 32);
    f32x4 ce2  = *(const f32x4*)(e2b);

    unsigned int m1[4], m2[4];
#pragma unroll
    for (int pt = 0; pt < 4; ++pt) { m1[pt] = 0x7F7FFFFFu; m2[pt] = 0x7F7FFFFFu; }

    for (int it = 0; it < 16; ++it) {
        // ---- prefetch next iteration's E fragments (1-deep pipeline)
        int nit = it < 15 ? it + 1 : 15;
        const _Float16* nph = ephb + (nit << 10);
        const _Float16* npl = eplb + (nit << 10);
        f16x8 neh0 = *(const f16x8*)(nph);
        f16x8 neh1 = *(const f16x8*)(nph + 32);
        f16x8 nel0 = *(const f16x8*)(npl);
        f16x8 nel1 = *(const f16x8*)(npl + 32);
        f32x4 ne2  = *(const f32x4*)(e2b + (nit << 4));

        unsigned int vidx = (unsigned int)(it * 4);
#pragma unroll
        for (int pt = 0; pt < 4; ++pt) {
            f16x8 xh0 = __builtin_bit_cast(f16x8, Xh0[pt]);
            f16x8 xl0 = __builtin_bit_cast(f16x8, Xl0[pt]);
            f16x8 xh1 = __builtin_bit_cast(f16x8, Xh1[pt]);
            f16x8 xl1 = __builtin_bit_cast(f16x8, Xl1[pt]);
            f32x4 acc = ce2;                // +e2+bias folded into init
            acc = __builtin_amdgcn_mfma_f32_16x16x32_f16(ceh0, xh0, acc, 0, 0, 0);
            acc = __builtin_amdgcn_mfma_f32_16x16x32_f16(ceh0, xl0, acc, 0, 0, 0);
            acc = __builtin_amdgcn_mfma_f32_16x16x32_f16(cel0, xh0, acc, 0, 0, 0);
            acc = __builtin_amdgcn_mfma_f32_16x16x32_f16(ceh1, xh1, acc, 0, 0, 0);
            acc = __builtin_amdgcn_mfma_f32_16x16x32_f16(ceh1, xl1, acc, 0, 0, 0);
            acc = __builtin_amdgcn_mfma_f32_16x16x32_f16(cel1, xh1, acc, 0, 0, 0);
#pragma unroll
            for (int r = 0; r < 4; ++r) {
                unsigned int key = (__float_as_uint(acc[r]) & 0xFFFFFFC0u)
                                 | (vidx + (unsigned int)r);
                unsigned int mx = key > m1[pt] ? key : m1[pt];
                m2[pt] = m2[pt] < mx ? m2[pt] : mx;
                m1[pt] = m1[pt] < key ? m1[pt] : key;
            }
        }
        ceh0 = neh0; ceh1 = neh1; cel0 = nel0; cel1 = nel1; ce2 = ne2;
    }

    // ---- unpack keys
    float f1[4], f2[4];
    int   i1[4];
#pragma unroll
    for (int pt = 0; pt < 4; ++pt) {
        unsigned int lm = m1[pt] & 63u;
        i1[pt] = wave * 256 + (int)(lm >> 2) * 16 + lrow * 4 + (int)(lm & 3u);
        f1[pt] = __uint_as_float(m1[pt] & 0xFFFFFFC0u);
        f2[pt] = __uint_as_float(m2[pt] & 0xFFFFFFC0u);
    }

    // ---- merge across lane-groups (4 lanes hold same position)
#pragma unroll
    for (int off = 16; off < 64; off <<= 1) {
#pragma unroll
        for (int pt = 0; pt < 4; ++pt) {
            float om1 = __shfl_xor(f1[pt], off);
            float om2 = __shfl_xor(f2[pt], off);
            int   oi  = __shfl_xor(i1[pt], off);
            bool take = (om1 < f1[pt]) || (om1 == f1[pt] && oi < i1[pt]);
            float loser = take ? f1[pt] : om1;
            f2[pt] = fminf(fminf(f2[pt], om2), loser);
            f1[pt] = take ? om1 : f1[pt];
            i1[pt] = take ? oi  : i1[pt];
        }
    }
    if (lane < 16) {
#pragma unroll
        for (int pt = 0; pt < 4; ++pt) {
            int p = pt * 16 + lane;
            sm1[wave * 64 + p] = f1[pt];
            sm2[wave * 64 + p] = f2[pt];
            si1[wave * 64 + p] = i1[pt];
        }
    }
    __syncthreads();

    // ---- merge across 4 waves, write idx, flag near-ties
    if (tid < 64) {
        float a1 = sm1[tid], a2 = sm2[tid];
        int   ai = si1[tid];
#pragma unroll
        for (int w = 1; w < 4; ++w) {
            float b1 = sm1[w * 64 + tid], b2 = sm2[w * 64 + tid];
            int   bi = si1[w * 64 + tid];
            bool take = (b1 < a1) || (b1 == a1 && bi < ai);
            float loser = take ? a1 : b1;
            a2 = fminf(fminf(a2, b2), loser);
            if (take) { a1 = b1; ai = bi; }
        }
        int n = posbase + tid;
        idxbuf[(k << 15) + n] = ai;
        if (a2 - a1 < MARGIN) {
            int slot = atomicAdd(flagcnt, 1);
            flaglist[slot] = (k << 15) + n;
        }
    }
}

// ---------------------------------------------------------------- exact rescore
__global__ void __launch_bounds__(256) k_rescore(
        const float* __restrict__ z, const float* __restrict__ emb,
        const float* __restrict__ e2g, const int* __restrict__ flagcnt,
        const int* __restrict__ flaglist, int* __restrict__ idxbuf) {
    __shared__ float xsh[64];
    __shared__ float rm[256];
    __shared__ int   ri[256];
    int tid = threadIdx.x;
    int nf = *flagcnt;
    for (int e = blockIdx.x; e < nf; e += gridDim.x) {
        int gp = flaglist[e];
        int k = gp >> 15, n = gp & 32767;
        int b = n >> 13, s = n & 8191;
        if (tid < 64)
            xsh[tid] = z[(((size_t)(b * CCH + k * DIM + tid)) << 13) + s];
        __syncthreads();
        float best = 3.4e38f;
        int   bi = 0;
        for (int c = tid; c < CODES; c += 256) {
            const float* ev = emb + ((size_t)k << 16) + ((size_t)c << 6);
            float a0 = 0.f, a1 = 0.f, a2 = 0.f, a3 = 0.f;
#pragma unroll
            for (int d = 0; d < DIM; d += 4) {
                a0 = fmaf(xsh[d + 0], ev[d + 0], a0);
                a1 = fmaf(xsh[d + 1], ev[d + 1], a1);
                a2 = fmaf(xsh[d + 2], ev[d + 2], a2);
                a3 = fmaf(xsh[d + 3], ev[d + 3], a3);
            }
            float dot = (a0 + a1) + (a2 + a3);
            // e2g carries +512 bias: constant shift, argmin unaffected
            float dist = fmaf(-2.f, dot, e2g[(k << 10) + c]);
            if (dist < best) { best = dist; bi = c; }
        }
        rm[tid] = best; ri[tid] = bi;
        __syncthreads();
        for (int off = 128; off; off >>= 1) {
            if (tid < off) {
                float bv = rm[tid + off]; int bx = ri[tid + off];
                if (bv < rm[tid] || (bv == rm[tid] && bx < ri[tid])) {
                    rm[tid] = bv; ri[tid] = bx;
                }
            }
            __syncthreads();
        }
        if (tid == 0) idxbuf[(k << 15) + n] = ri[0];
        __syncthreads();
    }
}

// ---------------------------------------------------------------- gather+loss
// 4 consecutive positions per thread -> float4 z loads / q stores.
__global__ void __launch_bounds__(256) k_quant(
        const float* __restrict__ z, const float* __restrict__ emb,
        const int* __restrict__ idxbuf, float* __restrict__ out,
        int* __restrict__ counts, float* __restrict__ partial) {
    int tid = threadIdx.x;
    int q = blockIdx.x * 256 + tid;       // quad index
    int n0 = q * 4;
    int k = blockIdx.y;
    int b = n0 >> 13;
    int s = n0 & 8191;

    int4 bi = *(const int4*)&idxbuf[(k << 15) + n0];
    const f32x4* e0 = (const f32x4*)(emb + ((size_t)k << 16) + ((size_t)bi.x << 6));
    const f32x4* e1 = (const f32x4*)(emb + ((size_t)k << 16) + ((size_t)bi.y << 6));
    const f32x4* e2 = (const f32x4*)(emb + ((size_t)k << 16) + ((size_t)bi.z << 6));
    const f32x4* e3 = (const f32x4*)(emb + ((size_t)k << 16) + ((size_t)bi.w << 6));
    size_t base = (((size_t)(b * CCH + k * DIM)) << 13) + s;

    float sq = 0.f;
#pragma unroll
    for (int j = 0; j < 16; ++j) {
        f32x4 q0 = e0[j], q1 = e1[j], q2 = e2[j], q3 = e3[j];
#pragma unroll
        for (int i = 0; i < 4; ++i) {
            int d = j * 4 + i;
            f32x4 zv = *(const f32x4*)(z + base + ((size_t)d << 13));
            f32x4 ov = {q0[i], q1[i], q2[i], q3[i]};
            *(f32x4*)(out + base + ((size_t)d << 13)) = ov;
            f32x4 df = zv - ov;
            sq = fmaf(df[0], df[0], sq);
            sq = fmaf(df[1], df[1], sq);
            sq = fmaf(df[2], df[2], sq);
            sq = fmaf(df[3], df[3], sq);
        }
    }

    out[ENC_OFF + (size_t)(n0 + 0) * NBOOKS + k] = (float)bi.x;
    out[ENC_OFF + (size_t)(n0 + 1) * NBOOKS + k] = (float)bi.y;
    out[ENC_OFF + (size_t)(n0 + 2) * NBOOKS + k] = (float)bi.z;
    out[ENC_OFF + (size_t)(n0 + 3) * NBOOKS + k] = (float)bi.w;
    atomicAdd(&counts[(k << 10) + bi.x], 1);
    atomicAdd(&counts[(k << 10) + bi.y], 1);
    atomicAdd(&counts[(k << 10) + bi.z], 1);
    atomicAdd(&counts[(k << 10) + bi.w], 1);

    for (int off = 32; off; off >>= 1) sq += __shfl_down(sq, off, 64);
    __shared__ float red[4];
    if ((tid & 63) == 0) red[tid >> 6] = sq;
    __syncthreads();
    if (tid == 0)
        partial[blockIdx.y * gridDim.x + blockIdx.x] = (red[0] + red[1]) + (red[2] + red[3]);
}

// ---------------------------------------------------------------- finalize
__global__ void __launch_bounds__(256) k_fin(
        const int* __restrict__ counts, const float* __restrict__ partial,
        float* __restrict__ out) {
    __shared__ float sh[256];
    int tid = threadIdx.x;

    sh[tid] = tid < 128 ? partial[tid] : 0.f;   // 32 blocks x 4 books
    __syncthreads();
    for (int off = 128; off; off >>= 1) {
        if (tid < off) sh[tid] += sh[tid + off];
        __syncthreads();
    }
    if (tid == 0) out[LOSS_OFF] = 0.25f * sh[0] / 8388608.f;

    float psum = 0.f;
    for (int k = 0; k < NBOOKS; ++k) {
        float h = 0.f;
        for (int c = tid; c < CODES; c += 256) {
            float p = (float)counts[(k << 10) + c] * (1.f / 32768.f);
            h += p * logf(p + 1e-10f);
        }
        __syncthreads();
        sh[tid] = h;
        __syncthreads();
        for (int off = 128; off; off >>= 1) {
            if (tid < off) sh[tid] += sh[tid + off];
            __syncthreads();
        }
        if (tid == 0) psum += expf(-sh[0]);
        __syncthreads();
    }
    if (tid == 0) out[PERP_OFF] = psum * (1.f / NBOOKS);
}

// ----------------------------------------------------------------
extern "C" void kernel_launch(void* const* d_in, const int* in_sizes, int n_in,
                              void* d_out, int out_size, void* d_ws, size_t ws_size,
                              hipStream_t stream) {
    const float* z   = (const float*)d_in[0];
    const float* emb = (const float*)d_in[1];
    float* out = (float*)d_out;
    char* ws = (char*)d_ws;

    float*    e2       = (float*)(ws + WS_E2);
    _Float16* ehi      = (_Float16*)(ws + WS_EHI);
    _Float16* elo      = (_Float16*)(ws + WS_ELO);
    int*      idxbuf   = (int*)(ws + WS_IDX);
    int*      counts   = (int*)(ws + WS_CNT);
    float*    partial  = (float*)(ws + WS_PART);
    int*      flagcnt  = (int*)(ws + WS_FLAGCNT);
    int*      flaglist = (int*)(ws + WS_FLAGS);

    k_eprep2<<<16, 256, 0, stream>>>(emb, e2, ehi, elo, counts, flagcnt);

    dim3 agrid(NPOS / 64, NBOOKS);
    k_argmin_mfma<<<agrid, 256, 0, stream>>>(z, e2, ehi, elo, idxbuf, flagcnt, flaglist);
    k_rescore<<<1024, 256, 0, stream>>>(z, emb, e2, flagcnt, flaglist, idxbuf);

    dim3 qgrid(NPOS / 1024, NBOOKS);
    k_quant<<<qgrid, 256, 0, stream>>>(z, emb, idxbuf, out, counts, partial);
    k_fin<<<1, 256, 0, stream>>>(counts, partial, out);
}